// Round 7
// baseline (52.535 us; speedup 1.0000x reference)
//
#include <hip/hip_runtime.h>

// anchors: (8192, 8, 768) fp32 = [n=8192 rows][COLS=6144 cols]
// loss = -((2*n*sum(a^2) - 2*dot(colsum, colsum)) / sqrt(768)) / (8*8)
//
// Atomic-free 3-phase. R6 change: ROWS_PER_CHUNK 64->32 (1536 blocks,
// 6 blocks/CU = 24 waves/CU, vs 12 before) + unroll 16 for deeper load
// pipelining. Atomics are gone so the extra blocks cost only 3 MB more
// partial-writes. Distinguishes latency-bound vs fabric-BW-bound pass1.

typedef float f32x4 __attribute__((ext_vector_type(4)));

constexpr int COLS   = 6144;       // k * dim_emb = 8 * 768
constexpr int COLS4  = COLS / 4;   // 1536 float4 per row
constexpr int BLK    = 256;
constexpr int STRIPS = COLS4 / BLK;            // 6 column strips
constexpr int ROWS_PER_CHUNK = 32;
constexpr int CHUNKS = 8192 / ROWS_PER_CHUNK;  // 256
constexpr int NBLK1  = STRIPS * CHUNKS;        // 1536

// ws layout (floats):
constexpr size_t PART_F = (size_t)CHUNKS * COLS4 * 4;   // partial: 6 MB
constexpr size_t SSQ_F  = PART_F;                       // ssq_arr[NBLK1]
constexpr size_t DOT_F  = PART_F + NBLK1;               // dotpart[STRIPS]
constexpr size_t SSQS_F = DOT_F + STRIPS;               // ssqsum[1]

__global__ void __launch_bounds__(BLK)
anchor_pass1(const f32x4* __restrict__ a,
             f32x4* __restrict__ partial,
             float* __restrict__ ssq_arr) {
    const int col4  = blockIdx.x * BLK + threadIdx.x;   // 0..COLS4-1
    const int chunk = blockIdx.y;
    const f32x4* p = a + (size_t)chunk * ROWS_PER_CHUNK * COLS4 + col4;

    f32x4 cs = (f32x4)(0.f);
    float ssq = 0.f;
    #pragma unroll 16
    for (int r = 0; r < ROWS_PER_CHUNK; ++r) {
        f32x4 v = p[(size_t)r * COLS4];
        cs += v;
        ssq = fmaf(v.x, v.x, ssq);
        ssq = fmaf(v.y, v.y, ssq);
        ssq = fmaf(v.z, v.z, ssq);
        ssq = fmaf(v.w, v.w, ssq);
    }

    partial[(size_t)chunk * COLS4 + col4] = cs;

    #pragma unroll
    for (int off = 32; off > 0; off >>= 1)
        ssq += __shfl_down(ssq, off, 64);
    __shared__ float wsum[BLK / 64];
    const int lane = threadIdx.x & 63, wid = threadIdx.x >> 6;
    if (lane == 0) wsum[wid] = ssq;
    __syncthreads();
    if (threadIdx.x == 0) {
        float s = 0.f;
        #pragma unroll
        for (int w = 0; w < BLK / 64; ++w) s += wsum[w];
        ssq_arr[blockIdx.y * STRIPS + blockIdx.x] = s;
    }
}

__global__ void __launch_bounds__(BLK)
anchor_pass2a(const f32x4* __restrict__ partial,
              const float* __restrict__ ssq_arr,
              float* __restrict__ dotpart,
              float* __restrict__ ssqsum) {
    const int j = blockIdx.x * BLK + threadIdx.x;   // f4-column 0..1535
    f32x4 cs = (f32x4)(0.f);
    #pragma unroll 8
    for (int c = 0; c < CHUNKS; ++c)
        cs += partial[(size_t)c * COLS4 + j];
    float dot = cs.x * cs.x + cs.y * cs.y + cs.z * cs.z + cs.w * cs.w;

    __shared__ float wsum[BLK / 64];
    const int lane = threadIdx.x & 63, wid = threadIdx.x >> 6;
    #pragma unroll
    for (int off = 32; off > 0; off >>= 1)
        dot += __shfl_down(dot, off, 64);
    if (lane == 0) wsum[wid] = dot;
    __syncthreads();
    if (threadIdx.x == 0) {
        float d = 0.f;
        #pragma unroll
        for (int w = 0; w < BLK / 64; ++w) d += wsum[w];
        dotpart[blockIdx.x] = d;
    }

    if (blockIdx.x == 0) {
        __syncthreads();                 // reuse wsum safely
        float s = 0.f;
        for (int i = threadIdx.x; i < NBLK1; i += BLK) s += ssq_arr[i];
        #pragma unroll
        for (int off = 32; off > 0; off >>= 1)
            s += __shfl_down(s, off, 64);
        if (lane == 0) wsum[wid] = s;
        __syncthreads();
        if (threadIdx.x == 0) {
            float t = 0.f;
            #pragma unroll
            for (int w = 0; w < BLK / 64; ++w) t += wsum[w];
            ssqsum[0] = t;
        }
    }
}

__global__ void __launch_bounds__(64)
anchor_pass2b(const float* __restrict__ dotpart,
              const float* __restrict__ ssqsum,
              float* __restrict__ out, int n_rows) {
    if (threadIdx.x == 0) {
        float dot = 0.f;
        #pragma unroll
        for (int i = 0; i < STRIPS; ++i) dot += dotpart[i];
        double pair = 2.0 * (double)n_rows * (double)ssqsum[0]
                    - 2.0 * (double)dot;
        const double factor = 27.712812921102035;  // sqrt(768)
        out[0] = (float)(-(pair / factor) / 64.0); // k*k = 64
    }
}

extern "C" void kernel_launch(void* const* d_in, const int* in_sizes, int n_in,
                              void* d_out, int out_size, void* d_ws, size_t ws_size,
                              hipStream_t stream) {
    const f32x4* a = (const f32x4*)d_in[0];
    float* ws      = (float*)d_ws;
    float* out     = (float*)d_out;
    const int n_rows = in_sizes[0] / COLS;  // 8192

    f32x4* partial = (f32x4*)ws;
    float* ssq_arr = ws + SSQ_F;
    float* dotpart = ws + DOT_F;
    float* ssqsum  = ws + SSQS_F;

    dim3 grid1(STRIPS, CHUNKS);
    anchor_pass1<<<grid1, BLK, 0, stream>>>(a, partial, ssq_arr);
    anchor_pass2a<<<STRIPS, BLK, 0, stream>>>(partial, ssq_arr, dotpart, ssqsum);
    anchor_pass2b<<<1, 64, 0, stream>>>(dotpart, ssqsum, out, n_rows);
}

// Round 8
// 49.107 us; speedup vs baseline: 1.0698x; 1.0698x over previous
//
#include <hip/hip_runtime.h>

// anchors: (8192, 8, 768) fp32 = [n=8192 rows][COLS=6144 cols]
// loss = (2*dot(colsum,colsum) - 2*n*sum(a^2)) / sqrt(768) / 64
//
// R8: contiguous-read pass1. Each block streams 16 FULL rows (384 KB
// contiguous) instead of a 24KB-strided column strip; per-thread acc[6]
// covers the 6 column-subtiles (statically indexed -> VGPRs).
// pass2b eliminated: loss is linear in {ssq, dot}; pass2a blocks
// atomicAdd scaled contributions into out[0], zeroed by pass1.

typedef float f32x4 __attribute__((ext_vector_type(4)));

constexpr int COLS   = 6144;
constexpr int COLS4  = COLS / 4;           // 1536
constexpr int BLK    = 256;
constexpr int ITERS  = COLS4 / BLK;        // 6 column-subtiles
constexpr int RPC    = 16;                 // rows per block
constexpr int CHUNKS = 8192 / RPC;         // 512 blocks (2/CU)

// ws floats: partial f32x4[CHUNKS][COLS4] (12 MB), then ssq_arr[CHUNKS]
constexpr size_t PART_F = (size_t)CHUNKS * COLS4 * 4;

__global__ void __launch_bounds__(BLK)
anchor_pass1(const f32x4* __restrict__ a,
             f32x4* __restrict__ partial,
             float* __restrict__ ssq_arr,
             float* __restrict__ out) {
    const int c = blockIdx.x;
    const int t = threadIdx.x;
    if (c == 0 && t == 0) out[0] = 0.f;    // accumulator for pass2a

    const f32x4* p = a + (size_t)c * RPC * COLS4 + t;

    f32x4 acc[ITERS];
    #pragma unroll
    for (int i = 0; i < ITERS; ++i) acc[i] = (f32x4)(0.f);
    float ssq = 0.f;

    #pragma unroll 2
    for (int r = 0; r < RPC; ++r) {
        #pragma unroll
        for (int i = 0; i < ITERS; ++i) {
            f32x4 v = p[(size_t)r * COLS4 + i * BLK];
            acc[i] += v;
            ssq = fmaf(v.x, v.x, ssq);
            ssq = fmaf(v.y, v.y, ssq);
            ssq = fmaf(v.z, v.z, ssq);
            ssq = fmaf(v.w, v.w, ssq);
        }
    }

    f32x4* q = partial + (size_t)c * COLS4 + t;
    #pragma unroll
    for (int i = 0; i < ITERS; ++i) q[i * BLK] = acc[i];

    #pragma unroll
    for (int off = 32; off > 0; off >>= 1)
        ssq += __shfl_down(ssq, off, 64);
    __shared__ float wsum[BLK / 64];
    const int lane = t & 63, wid = t >> 6;
    if (lane == 0) wsum[wid] = ssq;
    __syncthreads();
    if (t == 0) {
        float s = 0.f;
        #pragma unroll
        for (int w = 0; w < BLK / 64; ++w) s += wsum[w];
        ssq_arr[c] = s;
    }
}

// 24 blocks x 256 thr; block b owns col4 [b*64, b*64+64), 4 segs of chunks
__global__ void __launch_bounds__(BLK)
anchor_pass2a(const f32x4* __restrict__ partial,
              const float* __restrict__ ssq_arr,
              float* __restrict__ out, int n_rows) {
    const int t    = threadIdx.x;
    const int jl   = t & 63;
    const int seg  = t >> 6;               // 0..3
    const int col4 = blockIdx.x * 64 + jl;
    const int CPS  = CHUNKS / 4;           // 128 chunks per seg

    f32x4 cs = (f32x4)(0.f);
    #pragma unroll 4
    for (int i = 0; i < CPS; ++i)
        cs += partial[(size_t)(seg * CPS + i) * COLS4 + col4];

    __shared__ f32x4 sm[4][64];
    sm[seg][jl] = cs;
    __syncthreads();

    const double Cd = 2.0 / (27.712812921102035 * 64.0);  // 2/(sqrt(768)*k*k)

    if (t < 64) {
        f32x4 tot = sm[0][t] + sm[1][t] + sm[2][t] + sm[3][t];
        float d = tot.x * tot.x + tot.y * tot.y
                + tot.z * tot.z + tot.w * tot.w;
        #pragma unroll
        for (int off = 32; off > 0; off >>= 1)
            d += __shfl_down(d, off, 64);
        if (t == 0) atomicAdd(out, (float)(Cd * (double)d));
    }

    if (blockIdx.x == 0) {                  // uniform branch: whole block
        float s = 0.f;
        for (int i = t; i < CHUNKS; i += BLK) s += ssq_arr[i];
        #pragma unroll
        for (int off = 32; off > 0; off >>= 1)
            s += __shfl_down(s, off, 64);
        __shared__ float ws2[BLK / 64];
        if ((t & 63) == 0) ws2[t >> 6] = s;
        __syncthreads();
        if (t == 0) {
            float st = 0.f;
            #pragma unroll
            for (int w = 0; w < BLK / 64; ++w) st += ws2[w];
            atomicAdd(out, (float)(-Cd * (double)n_rows * (double)st));
        }
    }
}

extern "C" void kernel_launch(void* const* d_in, const int* in_sizes, int n_in,
                              void* d_out, int out_size, void* d_ws, size_t ws_size,
                              hipStream_t stream) {
    const f32x4* a = (const f32x4*)d_in[0];
    float* ws      = (float*)d_ws;
    float* out     = (float*)d_out;
    const int n_rows = in_sizes[0] / COLS;  // 8192

    f32x4* partial = (f32x4*)ws;
    float* ssq_arr = ws + PART_F;

    anchor_pass1<<<CHUNKS, BLK, 0, stream>>>(a, partial, ssq_arr, out);
    anchor_pass2a<<<COLS4 / 64, BLK, 0, stream>>>(partial, ssq_arr, out, n_rows);
}

// Round 9
// 40.563 us; speedup vs baseline: 1.2951x; 1.2106x over previous
//
#include <hip/hip_runtime.h>

// anchors: (8192, 8, 768) fp32 = [n=8192 rows][COLS=6144 cols]
// loss = (2*dot(colsum,colsum) - 2*n*sum(a^2)) / sqrt(768) / 64
//
// R9: pass1 identical to R6 (best measured: col-strip, RPC=64, 768 blocks).
// Tail consolidated into ONE pass2 dispatch (24 blocks):
//   - each block: dot-part over its 64 f4-columns -> atomicAdd(dotacc)
//   - block 0 additionally reduces ssq_arr -> atomicAdd(dotacc, -Cd*n*ssq)
//   - LAST block (fence-free R5 protocol: vmcnt(0) + relaxed agent counter,
//     agent-scope load) writes out[0].
// pass1 block(0,0) zeroes dotacc/cnt (prev-dispatch write -> visible).

typedef float f32x4 __attribute__((ext_vector_type(4)));

constexpr int COLS   = 6144;
constexpr int COLS4  = COLS / 4;           // 1536
constexpr int BLK    = 256;
constexpr int STRIPS = COLS4 / BLK;        // 6
constexpr int RPC    = 64;
constexpr int CHUNKS = 8192 / RPC;         // 128
constexpr int NBLK1  = STRIPS * CHUNKS;    // 768
constexpr int NBLK2  = COLS4 / 64;         // 24

// ws floats: partial f32x4[CHUNKS][COLS4] (3 MB) | ssq_arr[NBLK1] | dotacc | cnt
constexpr size_t PART_F = (size_t)CHUNKS * COLS4 * 4;
constexpr size_t SSQ_F  = PART_F;
constexpr size_t DOTA_F = PART_F + NBLK1;
constexpr size_t CNT_F  = DOTA_F + 1;

__global__ void __launch_bounds__(BLK)
anchor_pass1(const f32x4* __restrict__ a,
             f32x4* __restrict__ partial,
             float* __restrict__ ssq_arr,
             float* __restrict__ dotacc,
             unsigned* __restrict__ cnt) {
    const int col4  = blockIdx.x * BLK + threadIdx.x;   // 0..COLS4-1
    const int chunk = blockIdx.y;
    if (blockIdx.x == 0 && blockIdx.y == 0 && threadIdx.x == 0) {
        dotacc[0] = 0.f;
        cnt[0] = 0u;
    }
    const f32x4* p = a + (size_t)chunk * RPC * COLS4 + col4;

    f32x4 cs = (f32x4)(0.f);
    float ssq = 0.f;
    #pragma unroll 8
    for (int r = 0; r < RPC; ++r) {
        f32x4 v = p[(size_t)r * COLS4];
        cs += v;
        ssq = fmaf(v.x, v.x, ssq);
        ssq = fmaf(v.y, v.y, ssq);
        ssq = fmaf(v.z, v.z, ssq);
        ssq = fmaf(v.w, v.w, ssq);
    }

    partial[(size_t)chunk * COLS4 + col4] = cs;

    #pragma unroll
    for (int off = 32; off > 0; off >>= 1)
        ssq += __shfl_down(ssq, off, 64);
    __shared__ float wsum[BLK / 64];
    const int lane = threadIdx.x & 63, wid = threadIdx.x >> 6;
    if (lane == 0) wsum[wid] = ssq;
    __syncthreads();
    if (threadIdx.x == 0) {
        float s = 0.f;
        #pragma unroll
        for (int w = 0; w < BLK / 64; ++w) s += wsum[w];
        ssq_arr[blockIdx.y * STRIPS + blockIdx.x] = s;
    }
}

__global__ void __launch_bounds__(BLK)
anchor_pass2(const f32x4* __restrict__ partial,
             const float* __restrict__ ssq_arr,
             float* __restrict__ dotacc,
             unsigned* __restrict__ cnt,
             float* __restrict__ out, int n_rows) {
    const int t    = threadIdx.x;
    const int jl   = t & 63;
    const int seg  = t >> 6;                // 0..3 (one wave per seg)
    const int col4 = blockIdx.x * 64 + jl;
    const int CPS  = CHUNKS / 4;            // 32 chunks per seg

    const double Cd = 2.0 / (27.712812921102035 * 64.0); // 2/(sqrt(768)*k*k)

    f32x4 cs = (f32x4)(0.f);
    #pragma unroll 8
    for (int i = 0; i < CPS; ++i)
        cs += partial[(size_t)(seg * CPS + i) * COLS4 + col4];

    __shared__ f32x4 sm[4][64];
    sm[seg][jl] = cs;
    __syncthreads();

    if (t < 64) {
        f32x4 tot = sm[0][t] + sm[1][t] + sm[2][t] + sm[3][t];
        float d = tot.x * tot.x + tot.y * tot.y
                + tot.z * tot.z + tot.w * tot.w;
        #pragma unroll
        for (int off = 32; off > 0; off >>= 1)
            d += __shfl_down(d, off, 64);
        if (t == 0) atomicAdd(dotacc, (float)(Cd * (double)d));
    }

    if (blockIdx.x == 0) {                  // uniform branch: whole block
        float s = 0.f;
        for (int i = t; i < NBLK1; i += BLK) s += ssq_arr[i];
        #pragma unroll
        for (int off = 32; off > 0; off >>= 1)
            s += __shfl_down(s, off, 64);
        __shared__ float ws2[BLK / 64];
        if ((t & 63) == 0) ws2[t >> 6] = s;
        __syncthreads();
        if (t == 0) {
            float st = 0.f;
            #pragma unroll
            for (int w = 0; w < BLK / 64; ++w) st += ws2[w];
            atomicAdd(dotacc, (float)(-Cd * (double)n_rows * (double)st));
        }
    }

    // fence-free last-block finalize (R5-proven protocol, tiny scale)
    if (t == 0) {
        asm volatile("s_waitcnt vmcnt(0)" ::: "memory");
        unsigned prev = __hip_atomic_fetch_add(cnt, 1u, __ATOMIC_RELAXED,
                                               __HIP_MEMORY_SCOPE_AGENT);
        if (prev == (unsigned)gridDim.x - 1) {
            float v = __hip_atomic_load(dotacc, __ATOMIC_RELAXED,
                                        __HIP_MEMORY_SCOPE_AGENT);
            out[0] = v;
        }
    }
}

extern "C" void kernel_launch(void* const* d_in, const int* in_sizes, int n_in,
                              void* d_out, int out_size, void* d_ws, size_t ws_size,
                              hipStream_t stream) {
    const f32x4* a = (const f32x4*)d_in[0];
    float* ws      = (float*)d_ws;
    float* out     = (float*)d_out;
    const int n_rows = in_sizes[0] / COLS;  // 8192

    f32x4* partial   = (f32x4*)ws;
    float* ssq_arr   = ws + SSQ_F;
    float* dotacc    = ws + DOTA_F;
    unsigned* cnt    = (unsigned*)(ws + CNT_F);

    dim3 grid1(STRIPS, CHUNKS);
    anchor_pass1<<<grid1, BLK, 0, stream>>>(a, partial, ssq_arr, dotacc, cnt);
    anchor_pass2<<<NBLK2, BLK, 0, stream>>>(partial, ssq_arr, dotacc, cnt,
                                            out, n_rows);
}

// Round 10
// 40.490 us; speedup vs baseline: 1.2975x; 1.0018x over previous
//
#include <hip/hip_runtime.h>

// anchors: (8192, 8, 768) fp32 = [n=8192 rows][COLS=6144 cols]
// loss = (2*dot(colsum,colsum) - 2*n*sum(a^2)) / sqrt(768) / 64
//
// R10: identical to R9 except pass1's row loop unroll 8 -> 16 (isolated
// MLP test: 16 outstanding 16B loads per wave instead of 8; R7 bundled
// this with a block-count change that is the suspected regressor).

typedef float f32x4 __attribute__((ext_vector_type(4)));

constexpr int COLS   = 6144;
constexpr int COLS4  = COLS / 4;           // 1536
constexpr int BLK    = 256;
constexpr int STRIPS = COLS4 / BLK;        // 6
constexpr int RPC    = 64;
constexpr int CHUNKS = 8192 / RPC;         // 128
constexpr int NBLK1  = STRIPS * CHUNKS;    // 768
constexpr int NBLK2  = COLS4 / 64;         // 24

// ws floats: partial f32x4[CHUNKS][COLS4] (3 MB) | ssq_arr[NBLK1] | dotacc | cnt
constexpr size_t PART_F = (size_t)CHUNKS * COLS4 * 4;
constexpr size_t SSQ_F  = PART_F;
constexpr size_t DOTA_F = PART_F + NBLK1;
constexpr size_t CNT_F  = DOTA_F + 1;

__global__ void __launch_bounds__(BLK)
anchor_pass1(const f32x4* __restrict__ a,
             f32x4* __restrict__ partial,
             float* __restrict__ ssq_arr,
             float* __restrict__ dotacc,
             unsigned* __restrict__ cnt) {
    const int col4  = blockIdx.x * BLK + threadIdx.x;   // 0..COLS4-1
    const int chunk = blockIdx.y;
    if (blockIdx.x == 0 && blockIdx.y == 0 && threadIdx.x == 0) {
        dotacc[0] = 0.f;
        cnt[0] = 0u;
    }
    const f32x4* p = a + (size_t)chunk * RPC * COLS4 + col4;

    f32x4 cs = (f32x4)(0.f);
    float ssq = 0.f;
    #pragma unroll 16
    for (int r = 0; r < RPC; ++r) {
        f32x4 v = p[(size_t)r * COLS4];
        cs += v;
        ssq = fmaf(v.x, v.x, ssq);
        ssq = fmaf(v.y, v.y, ssq);
        ssq = fmaf(v.z, v.z, ssq);
        ssq = fmaf(v.w, v.w, ssq);
    }

    partial[(size_t)chunk * COLS4 + col4] = cs;

    #pragma unroll
    for (int off = 32; off > 0; off >>= 1)
        ssq += __shfl_down(ssq, off, 64);
    __shared__ float wsum[BLK / 64];
    const int lane = threadIdx.x & 63, wid = threadIdx.x >> 6;
    if (lane == 0) wsum[wid] = ssq;
    __syncthreads();
    if (threadIdx.x == 0) {
        float s = 0.f;
        #pragma unroll
        for (int w = 0; w < BLK / 64; ++w) s += wsum[w];
        ssq_arr[blockIdx.y * STRIPS + blockIdx.x] = s;
    }
}

__global__ void __launch_bounds__(BLK)
anchor_pass2(const f32x4* __restrict__ partial,
             const float* __restrict__ ssq_arr,
             float* __restrict__ dotacc,
             unsigned* __restrict__ cnt,
             float* __restrict__ out, int n_rows) {
    const int t    = threadIdx.x;
    const int jl   = t & 63;
    const int seg  = t >> 6;                // 0..3 (one wave per seg)
    const int col4 = blockIdx.x * 64 + jl;
    const int CPS  = CHUNKS / 4;            // 32 chunks per seg

    const double Cd = 2.0 / (27.712812921102035 * 64.0); // 2/(sqrt(768)*k*k)

    f32x4 cs = (f32x4)(0.f);
    #pragma unroll 8
    for (int i = 0; i < CPS; ++i)
        cs += partial[(size_t)(seg * CPS + i) * COLS4 + col4];

    __shared__ f32x4 sm[4][64];
    sm[seg][jl] = cs;
    __syncthreads();

    if (t < 64) {
        f32x4 tot = sm[0][t] + sm[1][t] + sm[2][t] + sm[3][t];
        float d = tot.x * tot.x + tot.y * tot.y
                + tot.z * tot.z + tot.w * tot.w;
        #pragma unroll
        for (int off = 32; off > 0; off >>= 1)
            d += __shfl_down(d, off, 64);
        if (t == 0) atomicAdd(dotacc, (float)(Cd * (double)d));
    }

    if (blockIdx.x == 0) {                  // uniform branch: whole block
        float s = 0.f;
        for (int i = t; i < NBLK1; i += BLK) s += ssq_arr[i];
        #pragma unroll
        for (int off = 32; off > 0; off >>= 1)
            s += __shfl_down(s, off, 64);
        __shared__ float ws2[BLK / 64];
        if ((t & 63) == 0) ws2[t >> 6] = s;
        __syncthreads();
        if (t == 0) {
            float st = 0.f;
            #pragma unroll
            for (int w = 0; w < BLK / 64; ++w) st += ws2[w];
            atomicAdd(dotacc, (float)(-Cd * (double)n_rows * (double)st));
        }
    }

    // fence-free last-block finalize (R5-proven protocol, tiny scale)
    if (t == 0) {
        asm volatile("s_waitcnt vmcnt(0)" ::: "memory");
        unsigned prev = __hip_atomic_fetch_add(cnt, 1u, __ATOMIC_RELAXED,
                                               __HIP_MEMORY_SCOPE_AGENT);
        if (prev == (unsigned)gridDim.x - 1) {
            float v = __hip_atomic_load(dotacc, __ATOMIC_RELAXED,
                                        __HIP_MEMORY_SCOPE_AGENT);
            out[0] = v;
        }
    }
}

extern "C" void kernel_launch(void* const* d_in, const int* in_sizes, int n_in,
                              void* d_out, int out_size, void* d_ws, size_t ws_size,
                              hipStream_t stream) {
    const f32x4* a = (const f32x4*)d_in[0];
    float* ws      = (float*)d_ws;
    float* out     = (float*)d_out;
    const int n_rows = in_sizes[0] / COLS;  // 8192

    f32x4* partial   = (f32x4*)ws;
    float* ssq_arr   = ws + SSQ_F;
    float* dotacc    = ws + DOTA_F;
    unsigned* cnt    = (unsigned*)(ws + CNT_F);

    dim3 grid1(STRIPS, CHUNKS);
    anchor_pass1<<<grid1, BLK, 0, stream>>>(a, partial, ssq_arr, dotacc, cnt);
    anchor_pass2<<<NBLK2, BLK, 0, stream>>>(partial, ssq_arr, dotacc, cnt,
                                            out, n_rows);
}